// Round 4
// baseline (191.986 us; speedup 1.0000x reference)
//
#include <hip/hip_runtime.h>
#include <cstdint>
#include <cstddef>

#define BB 2
#define CC 256
#define NN 16
#define LL 4096
#define NCH 128
#define CLEN 32
#define BKK 32
#define LOG2E 1.4426950408889634f

__device__ __forceinline__ float softplus_f(float z) {
    return fmaxf(z, 0.f) + log1pf(expf(-fabsf(z)));
}

// ---------------- K1: delta = softplus(X @ W_delta + b), du interleaved -----
// Tile 64l x 128c, 4l x 8c per thread, BK=32, double-buffered LDS (1 barrier
// per step), W_B/W_C via wave-uniform scalar loads. ct==0 blocks also emit
// Bm/Cm from the staged As tiles.
__global__ __launch_bounds__(256) void k1_delta_gemm(
    const float* __restrict__ feat, const float* __restrict__ Wd,
    const float* __restrict__ bd, const float* __restrict__ WB,
    const float* __restrict__ WC, float* __restrict__ du,
    float* __restrict__ Bm, float* __restrict__ Cm)
{
    int ct = blockIdx.x & 1;           // 2 c-tiles of 128
    int lt = (blockIdx.x >> 1) & 63;   // 64 l-tiles of 64
    int b  = blockIdx.x >> 7;
    int l0 = lt * 64, c0 = ct * 128;
    __shared__ float As[2][BKK][64];    // 16 KB
    __shared__ float Bs[2][BKK][128];   // 32 KB
    int tx = threadIdx.x & 15;          // c: 4 + 4 (stride-64 split)
    int ty = threadIdx.x >> 4;          // l: 4 each

    const float* fbase = feat + (size_t)b * CC * LL;
    const bool doBC = (ct == 0);
    int halfu = __builtin_amdgcn_readfirstlane(threadIdx.x >> 6);
    const float* wsel = (halfu >> 1) ? WC : WB;
    int nbu = (halfu & 1) * 8;
    int lloc = threadIdx.x & 63;

    // staging maps
    int qa0 = threadIdx.x,        ra0 = qa0 >> 4, ca0 = (qa0 & 15) * 4;
    int qa1 = threadIdx.x + 256,  ra1 = qa1 >> 4, ca1 = (qa1 & 15) * 4;
    int rb[4], cb[4];
    #pragma unroll
    for (int i = 0; i < 4; ++i) {
        int q = threadIdx.x + 256 * i;
        rb[i] = q >> 5; cb[i] = (q & 31) * 4;
    }

    float4 pa0, pa1, pb[4];
    // prefetch chunk 0
    pa0 = *(const float4*)&fbase[(size_t)ra0 * LL + l0 + ca0];
    pa1 = *(const float4*)&fbase[(size_t)ra1 * LL + l0 + ca1];
    #pragma unroll
    for (int i = 0; i < 4; ++i)
        pb[i] = *(const float4*)&Wd[(size_t)rb[i] * CC + c0 + cb[i]];
    *(float4*)&As[0][ra0][ca0] = pa0;
    *(float4*)&As[0][ra1][ca1] = pa1;
    #pragma unroll
    for (int i = 0; i < 4; ++i)
        *(float4*)&Bs[0][rb[i]][cb[i]] = pb[i];

    float acc[4][8] = {};
    float accBC[8] = {};
    int buf = 0;
    for (int s = 0; s < 8; ++s) {
        if (s < 7) {
            int k0 = (s + 1) * BKK;
            pa0 = *(const float4*)&fbase[(size_t)(k0 + ra0) * LL + l0 + ca0];
            pa1 = *(const float4*)&fbase[(size_t)(k0 + ra1) * LL + l0 + ca1];
            #pragma unroll
            for (int i = 0; i < 4; ++i)
                pb[i] = *(const float4*)&Wd[(size_t)(k0 + rb[i]) * CC + c0 + cb[i]];
        }
        __syncthreads();
        #pragma unroll
        for (int kk = 0; kk < BKK; ++kk) {
            float4 a  = *(float4*)&As[buf][kk][ty * 4];
            float4 b0 = *(float4*)&Bs[buf][kk][tx * 4];
            float4 b1 = *(float4*)&Bs[buf][kk][64 + tx * 4];
            float av[4] = {a.x, a.y, a.z, a.w};
            float bv[8] = {b0.x, b0.y, b0.z, b0.w, b1.x, b1.y, b1.z, b1.w};
            #pragma unroll
            for (int i = 0; i < 4; ++i)
                #pragma unroll
                for (int j = 0; j < 8; ++j)
                    acc[i][j] = fmaf(av[i], bv[j], acc[i][j]);
        }
        if (doBC) {
            int kb = s * BKK;
            #pragma unroll
            for (int kk = 0; kk < BKK; ++kk) {
                float xv = As[buf][kk][lloc];
                float4 w0 = *(const float4*)&wsel[(kb + kk) * 16 + nbu];
                float4 w1 = *(const float4*)&wsel[(kb + kk) * 16 + nbu + 4];
                accBC[0] = fmaf(xv, w0.x, accBC[0]);
                accBC[1] = fmaf(xv, w0.y, accBC[1]);
                accBC[2] = fmaf(xv, w0.z, accBC[2]);
                accBC[3] = fmaf(xv, w0.w, accBC[3]);
                accBC[4] = fmaf(xv, w1.x, accBC[4]);
                accBC[5] = fmaf(xv, w1.y, accBC[5]);
                accBC[6] = fmaf(xv, w1.z, accBC[6]);
                accBC[7] = fmaf(xv, w1.w, accBC[7]);
            }
        }
        if (s < 7) {
            *(float4*)&As[buf ^ 1][ra0][ca0] = pa0;
            *(float4*)&As[buf ^ 1][ra1][ca1] = pa1;
            #pragma unroll
            for (int i = 0; i < 4; ++i)
                *(float4*)&Bs[buf ^ 1][rb[i]][cb[i]] = pb[i];
        }
        buf ^= 1;
    }

    if (doBC) {
        float* dst = ((halfu >> 1) ? Cm : Bm) + ((size_t)b * LL + l0 + lloc) * NN + nbu;
        *(float4*)&dst[0] = make_float4(accBC[0], accBC[1], accBC[2], accBC[3]);
        *(float4*)&dst[4] = make_float4(accBC[4], accBC[5], accBC[6], accBC[7]);
    }

    // epilogue: softplus + u = delta*x, du interleaved pairs
    float bdv[8];
    #pragma unroll
    for (int g = 0; g < 2; ++g)
        #pragma unroll
        for (int j = 0; j < 4; ++j) bdv[g * 4 + j] = bd[c0 + g * 64 + tx * 4 + j];
    // feat[c][l] tiles for u
    float fc[4][8];
    #pragma unroll
    for (int g = 0; g < 2; ++g)
        #pragma unroll
        for (int j = 0; j < 4; ++j) {
            float4 v = *(const float4*)&fbase[(size_t)(c0 + g * 64 + tx * 4 + j) * LL + l0 + ty * 4];
            fc[0][g * 4 + j] = v.x; fc[1][g * 4 + j] = v.y;
            fc[2][g * 4 + j] = v.z; fc[3][g * 4 + j] = v.w;
        }
    float4* du4 = (float4*)du;
    #pragma unroll
    for (int i = 0; i < 4; ++i) {
        int l = l0 + ty * 4 + i;
        #pragma unroll
        for (int g = 0; g < 2; ++g) {
            float dv[4], uv[4];
            #pragma unroll
            for (int j = 0; j < 4; ++j) {
                float z = acc[i][g * 4 + j] + bdv[g * 4 + j];
                dv[j] = softplus_f(z);
                uv[j] = dv[j] * fc[i][g * 4 + j];
            }
            size_t o = (((size_t)b * LL + l) * CC + c0 + g * 64 + tx * 4) >> 1;
            du4[o]     = make_float4(dv[0], uv[0], dv[1], uv[1]);
            du4[o + 1] = make_float4(dv[2], uv[2], dv[3], uv[3]);
        }
    }
}

// ---------------- P1: per-chunk aggregates for 3 order-classes --------------
__global__ __launch_bounds__(256, 4) void p1_aggr(
    const float2* __restrict__ du, const float* __restrict__ Bm,
    const float* __restrict__ A_log, float* __restrict__ P, float* __restrict__ S)
{
    int blk = blockIdx.x;
    int cls = blk >> 8;
    int b   = (blk >> 7) & 1;
    int ch  = blk & 127;
    int p0, inner;
    if (cls == 0)      { p0 = 32 * ch;        inner = 1; }
    else if (cls == 1) { p0 = 4095 - 32 * ch; inner = -1; }
    else               { p0 = 63 - (ch >> 1) + 2048 * (ch & 1); inner = 64; }
    int c = threadIdx.x;
    __shared__ float sBm[CLEN * NN];
    for (int i = threadIdx.x; i < CLEN * NN; i += 256) {
        int j = i >> 4, n = i & 15;
        sBm[i] = Bm[((size_t)b * LL + (p0 + inner * j)) * NN + n];
    }
    float A2[NN];
    {
        const float4* al = (const float4*)(A_log + c * NN);
        #pragma unroll
        for (int q = 0; q < 4; ++q) {
            float4 v = al[q];
            A2[q*4+0] = -expf(v.x) * LOG2E;
            A2[q*4+1] = -expf(v.y) * LOG2E;
            A2[q*4+2] = -expf(v.z) * LOG2E;
            A2[q*4+3] = -expf(v.w) * LOG2E;
        }
    }
    __syncthreads();
    float Sv[NN] = {};
    float sumd = 0.f;
    const float2* dub = du + (size_t)b * LL * CC + c;
    for (int j = 0; j < CLEN; ++j) {
        float2 dv = dub[(size_t)(p0 + inner * j) * CC];
        sumd += dv.x;
        float dA[NN];
        #pragma unroll
        for (int n = 0; n < NN; ++n) dA[n] = __builtin_amdgcn_exp2f(A2[n] * dv.x);
        #pragma unroll
        for (int n = 0; n < NN; ++n)
            Sv[n] = fmaf(dA[n], Sv[n], dv.y * sBm[j * 16 + n]);
    }
    size_t base = ((size_t)((cls * 2 + b) * 128 + ch)) * 4096 + (size_t)c * 16;
    #pragma unroll
    for (int n = 0; n < NN; ++n) {
        P[base + n] = __builtin_amdgcn_exp2f(A2[n] * sumd);
        S[base + n] = Sv[n];
    }
}

// ---------------- P2: scan chunk aggregates per direction -> Hin ------------
__global__ __launch_bounds__(128) void p2_scan(
    const float* __restrict__ P, const float* __restrict__ S, float* __restrict__ Hin)
{
    int r = blockIdx.x * 128 + threadIdx.x;   // 32768 rows
    int cn = r & 4095;
    int db = r >> 12;
    int d = db >> 1;
    int cls = (d == 1) ? 1 : ((d == 3) ? 2 : 0);
    int b = db & 1;
    const size_t cbase = ((size_t)(cls * 2 + b) * 128) * 4096 + cn;
    const size_t obase = ((size_t)db * 128) * 4096 + cn;
    float h = 0.f;
    for (int g = 0; g < 16; ++g) {
        float pv[8], sv[8];
        #pragma unroll
        for (int i = 0; i < 8; ++i) {
            int ch = g * 8 + i;
            int chm = (d == 2) ? (126 - 2 * (ch >> 1) + (ch & 1)) : ch;
            size_t ix = cbase + (size_t)chm * 4096;
            pv[i] = P[ix];
            sv[i] = S[ix];
        }
        #pragma unroll
        for (int i = 0; i < 8; ++i) {
            Hin[obase + (size_t)(g * 8 + i) * 4096] = h;
            h = fmaf(pv[i], h, sv[i]);
        }
    }
}

// ---------------- P3: replay chunks. sec0: d0+d2 shared; sec1: d1; sec2: d3 -
__global__ __launch_bounds__(256, 4) void p3_replay(
    const float2* __restrict__ du, const float* __restrict__ Bm,
    const float* __restrict__ Cm, const float* __restrict__ A_log,
    const float* __restrict__ Hin, float* __restrict__ yA,
    float* __restrict__ yB, float* __restrict__ yC)
{
    int blk = blockIdx.x;
    int sec = blk >> 8;
    int b   = (blk >> 7) & 1;
    int ch  = blk & 127;
    int p0, inner;
    if (sec == 0)      { p0 = 32 * ch;        inner = 1; }
    else if (sec == 1) { p0 = 4095 - 32 * ch; inner = -1; }
    else               { p0 = 63 - (ch >> 1) + 2048 * (ch & 1); inner = 64; }
    int c = threadIdx.x;
    __shared__ float sBm[CLEN * NN];
    __shared__ float sCm[CLEN * NN];
    for (int i = threadIdx.x; i < CLEN * NN; i += 256) {
        int j = i >> 4, n = i & 15;
        size_t o = ((size_t)b * LL + (p0 + inner * j)) * NN + n;
        sBm[i] = Bm[o];
        sCm[i] = Cm[o];
    }
    float A2[NN];
    {
        const float4* al = (const float4*)(A_log + c * NN);
        #pragma unroll
        for (int q = 0; q < 4; ++q) {
            float4 v = al[q];
            A2[q*4+0] = -expf(v.x) * LOG2E;
            A2[q*4+1] = -expf(v.y) * LOG2E;
            A2[q*4+2] = -expf(v.z) * LOG2E;
            A2[q*4+3] = -expf(v.w) * LOG2E;
        }
    }
    const float2* dub = du + (size_t)b * LL * CC + c;

    if (sec == 0) {
        int ch2 = 126 - (ch & ~1) + (ch & 1);
        float h0[NN], h2[NN];
        {
            const float4* hp0 = (const float4*)(Hin + ((size_t)(0 * 2 + b) * 128 + ch)  * 4096 + (size_t)c * 16);
            const float4* hp2 = (const float4*)(Hin + ((size_t)(2 * 2 + b) * 128 + ch2) * 4096 + (size_t)c * 16);
            #pragma unroll
            for (int q = 0; q < 4; ++q) {
                float4 v0 = hp0[q], v2 = hp2[q];
                h0[q*4+0]=v0.x; h0[q*4+1]=v0.y; h0[q*4+2]=v0.z; h0[q*4+3]=v0.w;
                h2[q*4+0]=v2.x; h2[q*4+1]=v2.y; h2[q*4+2]=v2.z; h2[q*4+3]=v2.w;
            }
        }
        __syncthreads();
        for (int j = 0; j < CLEN; ++j) {
            int p = p0 + j;
            float2 dv = dub[(size_t)p * CC];
            float dA[NN];
            #pragma unroll
            for (int n = 0; n < NN; ++n) dA[n] = __builtin_amdgcn_exp2f(A2[n] * dv.x);
            float y0v = 0.f, y2v = 0.f;
            #pragma unroll
            for (int n = 0; n < NN; ++n) {
                float Bu = dv.y * sBm[j * 16 + n];
                float cm = sCm[j * 16 + n];
                h0[n] = fmaf(dA[n], h0[n], Bu);
                h2[n] = fmaf(dA[n], h2[n], Bu);
                y0v = fmaf(h0[n], cm, y0v);
                y2v = fmaf(h2[n], cm, y2v);
            }
            yA[((size_t)b * LL + p) * CC + c] = 0.25f * (y0v + y2v);
        }
    } else {
        int d = (sec == 1) ? 1 : 3;
        float h[NN];
        {
            const float4* hp = (const float4*)(Hin + ((size_t)(d * 2 + b) * 128 + ch) * 4096 + (size_t)c * 16);
            #pragma unroll
            for (int q = 0; q < 4; ++q) {
                float4 v = hp[q];
                h[q*4+0]=v.x; h[q*4+1]=v.y; h[q*4+2]=v.z; h[q*4+3]=v.w;
            }
        }
        __syncthreads();
        float* yD = (sec == 1) ? yB : yC;
        for (int j = 0; j < CLEN; ++j) {
            int p = p0 + inner * j;
            float2 dv = dub[(size_t)p * CC];
            float dA[NN];
            #pragma unroll
            for (int n = 0; n < NN; ++n) dA[n] = __builtin_amdgcn_exp2f(A2[n] * dv.x);
            float yv = 0.f;
            #pragma unroll
            for (int n = 0; n < NN; ++n) {
                float Bu = dv.y * sBm[j * 16 + n];
                h[n] = fmaf(dA[n], h[n], Bu);
                yv = fmaf(h[n], sCm[j * 16 + n], yv);
            }
            yD[((size_t)b * LL + p) * CC + c] = 0.25f * yv;
        }
    }
}

// ---------------- K6: sum 3 y-buffers + x*D, transpose to (B,C,L) -----------
__global__ __launch_bounds__(256) void k6_reduce(
    const float* __restrict__ feat, const float* __restrict__ D,
    const float* __restrict__ yA, const float* __restrict__ yB,
    const float* __restrict__ yC, float* __restrict__ out)
{
    int pt = blockIdx.x & 63;
    int ct = (blockIdx.x >> 6) & 3;
    int b  = blockIdx.x >> 8;
    int p0 = pt * 64, c0 = ct * 64;
    __shared__ float tile[64 * 65];
    {
        int cl = threadIdx.x & 63;
        int pg = threadIdx.x >> 6;
        #pragma unroll
        for (int pp = 0; pp < 16; ++pp) {
            int pl = pp * 4 + pg;
            size_t ix = ((size_t)b * LL + p0 + pl) * CC + c0 + cl;
            tile[cl * 65 + pl] = yA[ix] + yB[ix] + yC[ix];
        }
    }
    __syncthreads();
    {
        int pl = threadIdx.x & 63;
        int cg = threadIdx.x >> 6;
        #pragma unroll
        for (int cc = 0; cc < 16; ++cc) {
            int cloc = cc * 4 + cg;
            int c = c0 + cloc;
            size_t o = ((size_t)b * CC + c) * LL + p0 + pl;
            out[o] = tile[cloc * 65 + pl] + feat[o] * D[c];
        }
    }
}

extern "C" void kernel_launch(void* const* d_in, const int* in_sizes, int n_in,
                              void* d_out, int out_size, void* d_ws, size_t ws_size,
                              hipStream_t stream)
{
    const float* feat  = (const float*)d_in[0];
    const float* A_log = (const float*)d_in[1];
    const float* D     = (const float*)d_in[2];
    const float* Wd    = (const float*)d_in[3];
    const float* bd    = (const float*)d_in[4];
    const float* WB    = (const float*)d_in[5];
    const float* WC    = (const float*)d_in[6];
    float* out = (float*)d_out;

    float* ws  = (float*)d_ws;
    float* du  = ws;                                      //  4,194,304 (float2 pairs)
    float* Bm  = du  + (size_t)4194304;                   //    131,072
    float* Cm  = Bm  + (size_t)131072;                    //    131,072
    float* P   = Cm  + (size_t)131072;                    //  3,145,728 (3 cls)
    float* S   = P   + (size_t)3145728;                   //  3,145,728
    float* Hin = S   + (size_t)3145728;                   //  4,194,304 (4 dirs)
    float* yA  = Hin + (size_t)4194304;                   //  2,097,152
    float* yB  = yA  + (size_t)2097152;                   //  2,097,152
    float* yC  = yB  + (size_t)2097152;                   //  2,097,152

    k1_delta_gemm<<<256, 256, 0, stream>>>(feat, Wd, bd, WB, WC, du, Bm, Cm);
    p1_aggr<<<768, 256, 0, stream>>>((const float2*)du, Bm, A_log, P, S);
    p2_scan<<<256, 128, 0, stream>>>(P, S, Hin);
    p3_replay<<<768, 256, 0, stream>>>((const float2*)du, Bm, Cm, A_log, Hin, yA, yB, yC);
    k6_reduce<<<512, 256, 0, stream>>>(feat, D, yA, yB, yC, out);
}

// Round 5
// 177.597 us; speedup vs baseline: 1.0810x; 1.0810x over previous
//
#include <hip/hip_runtime.h>
#include <cstdint>
#include <cstddef>

#define BB 2
#define CC 256
#define NN 16
#define LL 4096
#define NCH 128
#define CLEN 32
#define LCH 16          // l-chunk per k1 block
#define LOG2E 1.4426950408889634f

__device__ __forceinline__ float softplus_f(float z) {
    return fmaxf(z, 0.f) + log1pf(expf(-fabsf(z)));
}

// ---------------- K1: delta/u + Bm/Cm in one LDS-free, barrier-free sweep ---
// thread = c (256), block = (b, l-chunk of 16). feat[k][l] is wave-uniform ->
// scalar loads; Wd[k][c] is a coalesced vector load (L2-resident, 256 KB).
// No LDS, no __syncthreads, fp32 FMA in k-ascending order (same as before).
__global__ __launch_bounds__(256) void k1_delta_gemm(
    const float* __restrict__ feat, const float* __restrict__ Wd,
    const float* __restrict__ bd, const float* __restrict__ WB,
    const float* __restrict__ WC, float* __restrict__ du,
    float* __restrict__ Bm, float* __restrict__ Cm)
{
    int lc = blockIdx.x & 255;          // 256 l-chunks of 16
    int b  = blockIdx.x >> 8;
    int l0 = lc * LCH;
    int c  = threadIdx.x;
    const float* fbase = feat + (size_t)b * CC * LL;

    // Bm/Cm mapping: 16 threads per l; s<8 -> Bm, s>=8 -> Cm; 2 n's each
    int lB  = threadIdx.x >> 4;         // 0..15
    int s   = threadIdx.x & 15;
    int mat = s >> 3;                   // 0=Bm 1=Cm
    int n0  = (s & 7) * 2;
    const float* wBC = mat ? WC : WB;

    float accM[LCH] = {};
    float accB0 = 0.f, accB1 = 0.f;

    #pragma unroll 4
    for (int k = 0; k < 256; ++k) {
        const float* frow = fbase + (size_t)k * LL + l0;
        // wave-uniform feat chunk (16 floats) -> scalar loads
        float4 x0 = *(const float4*)(frow + 0);
        float4 x1 = *(const float4*)(frow + 4);
        float4 x2 = *(const float4*)(frow + 8);
        float4 x3 = *(const float4*)(frow + 12);
        // per-thread W column element (coalesced)
        float wv = Wd[(size_t)k * CC + c];
        // BC operands
        float2 wb = *(const float2*)&wBC[k * NN + n0];
        float xb = frow[lB];

        accM[0]  = fmaf(x0.x, wv, accM[0]);
        accM[1]  = fmaf(x0.y, wv, accM[1]);
        accM[2]  = fmaf(x0.z, wv, accM[2]);
        accM[3]  = fmaf(x0.w, wv, accM[3]);
        accM[4]  = fmaf(x1.x, wv, accM[4]);
        accM[5]  = fmaf(x1.y, wv, accM[5]);
        accM[6]  = fmaf(x1.z, wv, accM[6]);
        accM[7]  = fmaf(x1.w, wv, accM[7]);
        accM[8]  = fmaf(x2.x, wv, accM[8]);
        accM[9]  = fmaf(x2.y, wv, accM[9]);
        accM[10] = fmaf(x2.z, wv, accM[10]);
        accM[11] = fmaf(x2.w, wv, accM[11]);
        accM[12] = fmaf(x3.x, wv, accM[12]);
        accM[13] = fmaf(x3.y, wv, accM[13]);
        accM[14] = fmaf(x3.z, wv, accM[14]);
        accM[15] = fmaf(x3.w, wv, accM[15]);
        accB0 = fmaf(xb, wb.x, accB0);
        accB1 = fmaf(xb, wb.y, accB1);
    }

    // Bm/Cm store (each (l,n) pair computed exactly once)
    {
        float* dst = (mat ? Cm : Bm) + ((size_t)b * LL + l0 + lB) * NN + n0;
        *(float2*)dst = make_float2(accB0, accB1);
    }

    // epilogue: delta = softplus(acc + bd), u = delta * x
    float bdc = bd[c];
    float4 fx[4];
    {
        const float* fcp = fbase + (size_t)c * LL + l0;
        fx[0] = *(const float4*)(fcp + 0);
        fx[1] = *(const float4*)(fcp + 4);
        fx[2] = *(const float4*)(fcp + 8);
        fx[3] = *(const float4*)(fcp + 12);
    }
    float2* du2 = (float2*)du;
    const float* fxs = (const float*)fx;
    #pragma unroll
    for (int j = 0; j < LCH; ++j) {
        float dv = softplus_f(accM[j] + bdc);
        float uv = dv * fxs[j];
        du2[((size_t)b * LL + l0 + j) * CC + c] = make_float2(dv, uv);
    }
}

// ---------------- P1: per-chunk aggregates for 3 order-classes --------------
__global__ __launch_bounds__(256, 4) void p1_aggr(
    const float2* __restrict__ du, const float* __restrict__ Bm,
    const float* __restrict__ A_log, float* __restrict__ P, float* __restrict__ S)
{
    int blk = blockIdx.x;
    int cls = blk >> 8;
    int b   = (blk >> 7) & 1;
    int ch  = blk & 127;
    int p0, inner;
    if (cls == 0)      { p0 = 32 * ch;        inner = 1; }
    else if (cls == 1) { p0 = 4095 - 32 * ch; inner = -1; }
    else               { p0 = 63 - (ch >> 1) + 2048 * (ch & 1); inner = 64; }
    int c = threadIdx.x;
    __shared__ float sBm[CLEN * NN];
    for (int i = threadIdx.x; i < CLEN * NN; i += 256) {
        int j = i >> 4, n = i & 15;
        sBm[i] = Bm[((size_t)b * LL + (p0 + inner * j)) * NN + n];
    }
    float A2[NN];
    {
        const float4* al = (const float4*)(A_log + c * NN);
        #pragma unroll
        for (int q = 0; q < 4; ++q) {
            float4 v = al[q];
            A2[q*4+0] = -expf(v.x) * LOG2E;
            A2[q*4+1] = -expf(v.y) * LOG2E;
            A2[q*4+2] = -expf(v.z) * LOG2E;
            A2[q*4+3] = -expf(v.w) * LOG2E;
        }
    }
    __syncthreads();
    float Sv[NN] = {};
    float sumd = 0.f;
    const float2* dub = du + (size_t)b * LL * CC + c;
    for (int j = 0; j < CLEN; ++j) {
        float2 dv = dub[(size_t)(p0 + inner * j) * CC];
        sumd += dv.x;
        float dA[NN];
        #pragma unroll
        for (int n = 0; n < NN; ++n) dA[n] = __builtin_amdgcn_exp2f(A2[n] * dv.x);
        #pragma unroll
        for (int n = 0; n < NN; ++n)
            Sv[n] = fmaf(dA[n], Sv[n], dv.y * sBm[j * 16 + n]);
    }
    size_t base = ((size_t)((cls * 2 + b) * 128 + ch)) * 4096 + (size_t)c * 16;
    #pragma unroll
    for (int n = 0; n < NN; ++n) {
        P[base + n] = __builtin_amdgcn_exp2f(A2[n] * sumd);
        S[base + n] = Sv[n];
    }
}

// ---------------- P2: scan chunk aggregates per direction -> Hin ------------
__global__ __launch_bounds__(128) void p2_scan(
    const float* __restrict__ P, const float* __restrict__ S, float* __restrict__ Hin)
{
    int r = blockIdx.x * 128 + threadIdx.x;   // 32768 rows
    int cn = r & 4095;
    int db = r >> 12;
    int d = db >> 1;
    int cls = (d == 1) ? 1 : ((d == 3) ? 2 : 0);
    int b = db & 1;
    const size_t cbase = ((size_t)(cls * 2 + b) * 128) * 4096 + cn;
    const size_t obase = ((size_t)db * 128) * 4096 + cn;
    float h = 0.f;
    for (int g = 0; g < 16; ++g) {
        float pv[8], sv[8];
        #pragma unroll
        for (int i = 0; i < 8; ++i) {
            int ch = g * 8 + i;
            int chm = (d == 2) ? (126 - 2 * (ch >> 1) + (ch & 1)) : ch;
            size_t ix = cbase + (size_t)chm * 4096;
            pv[i] = P[ix];
            sv[i] = S[ix];
        }
        #pragma unroll
        for (int i = 0; i < 8; ++i) {
            Hin[obase + (size_t)(g * 8 + i) * 4096] = h;
            h = fmaf(pv[i], h, sv[i]);
        }
    }
}

// ---------------- P3: replay chunks. sec0: d0+d2 shared; sec1: d1; sec2: d3 -
__global__ __launch_bounds__(256, 4) void p3_replay(
    const float2* __restrict__ du, const float* __restrict__ Bm,
    const float* __restrict__ Cm, const float* __restrict__ A_log,
    const float* __restrict__ Hin, float* __restrict__ yA,
    float* __restrict__ yB, float* __restrict__ yC)
{
    int blk = blockIdx.x;
    int sec = blk >> 8;
    int b   = (blk >> 7) & 1;
    int ch  = blk & 127;
    int p0, inner;
    if (sec == 0)      { p0 = 32 * ch;        inner = 1; }
    else if (sec == 1) { p0 = 4095 - 32 * ch; inner = -1; }
    else               { p0 = 63 - (ch >> 1) + 2048 * (ch & 1); inner = 64; }
    int c = threadIdx.x;
    __shared__ float sBm[CLEN * NN];
    __shared__ float sCm[CLEN * NN];
    for (int i = threadIdx.x; i < CLEN * NN; i += 256) {
        int j = i >> 4, n = i & 15;
        size_t o = ((size_t)b * LL + (p0 + inner * j)) * NN + n;
        sBm[i] = Bm[o];
        sCm[i] = Cm[o];
    }
    float A2[NN];
    {
        const float4* al = (const float4*)(A_log + c * NN);
        #pragma unroll
        for (int q = 0; q < 4; ++q) {
            float4 v = al[q];
            A2[q*4+0] = -expf(v.x) * LOG2E;
            A2[q*4+1] = -expf(v.y) * LOG2E;
            A2[q*4+2] = -expf(v.z) * LOG2E;
            A2[q*4+3] = -expf(v.w) * LOG2E;
        }
    }
    const float2* dub = du + (size_t)b * LL * CC + c;

    if (sec == 0) {
        int ch2 = 126 - (ch & ~1) + (ch & 1);
        float h0[NN], h2[NN];
        {
            const float4* hp0 = (const float4*)(Hin + ((size_t)(0 * 2 + b) * 128 + ch)  * 4096 + (size_t)c * 16);
            const float4* hp2 = (const float4*)(Hin + ((size_t)(2 * 2 + b) * 128 + ch2) * 4096 + (size_t)c * 16);
            #pragma unroll
            for (int q = 0; q < 4; ++q) {
                float4 v0 = hp0[q], v2 = hp2[q];
                h0[q*4+0]=v0.x; h0[q*4+1]=v0.y; h0[q*4+2]=v0.z; h0[q*4+3]=v0.w;
                h2[q*4+0]=v2.x; h2[q*4+1]=v2.y; h2[q*4+2]=v2.z; h2[q*4+3]=v2.w;
            }
        }
        __syncthreads();
        for (int j = 0; j < CLEN; ++j) {
            int p = p0 + j;
            float2 dv = dub[(size_t)p * CC];
            float dA[NN];
            #pragma unroll
            for (int n = 0; n < NN; ++n) dA[n] = __builtin_amdgcn_exp2f(A2[n] * dv.x);
            float y0v = 0.f, y2v = 0.f;
            #pragma unroll
            for (int n = 0; n < NN; ++n) {
                float Bu = dv.y * sBm[j * 16 + n];
                float cm = sCm[j * 16 + n];
                h0[n] = fmaf(dA[n], h0[n], Bu);
                h2[n] = fmaf(dA[n], h2[n], Bu);
                y0v = fmaf(h0[n], cm, y0v);
                y2v = fmaf(h2[n], cm, y2v);
            }
            yA[((size_t)b * LL + p) * CC + c] = 0.25f * (y0v + y2v);
        }
    } else {
        int d = (sec == 1) ? 1 : 3;
        float h[NN];
        {
            const float4* hp = (const float4*)(Hin + ((size_t)(d * 2 + b) * 128 + ch) * 4096 + (size_t)c * 16);
            #pragma unroll
            for (int q = 0; q < 4; ++q) {
                float4 v = hp[q];
                h[q*4+0]=v.x; h[q*4+1]=v.y; h[q*4+2]=v.z; h[q*4+3]=v.w;
            }
        }
        __syncthreads();
        float* yD = (sec == 1) ? yB : yC;
        for (int j = 0; j < CLEN; ++j) {
            int p = p0 + inner * j;
            float2 dv = dub[(size_t)p * CC];
            float dA[NN];
            #pragma unroll
            for (int n = 0; n < NN; ++n) dA[n] = __builtin_amdgcn_exp2f(A2[n] * dv.x);
            float yv = 0.f;
            #pragma unroll
            for (int n = 0; n < NN; ++n) {
                float Bu = dv.y * sBm[j * 16 + n];
                h[n] = fmaf(dA[n], h[n], Bu);
                yv = fmaf(h[n], sCm[j * 16 + n], yv);
            }
            yD[((size_t)b * LL + p) * CC + c] = 0.25f * yv;
        }
    }
}

// ---------------- K6: sum 3 y-buffers + x*D, transpose to (B,C,L) -----------
__global__ __launch_bounds__(256) void k6_reduce(
    const float* __restrict__ feat, const float* __restrict__ D,
    const float* __restrict__ yA, const float* __restrict__ yB,
    const float* __restrict__ yC, float* __restrict__ out)
{
    int pt = blockIdx.x & 63;
    int ct = (blockIdx.x >> 6) & 3;
    int b  = blockIdx.x >> 8;
    int p0 = pt * 64, c0 = ct * 64;
    __shared__ float tile[64 * 65];
    {
        int cl = threadIdx.x & 63;
        int pg = threadIdx.x >> 6;
        #pragma unroll
        for (int pp = 0; pp < 16; ++pp) {
            int pl = pp * 4 + pg;
            size_t ix = ((size_t)b * LL + p0 + pl) * CC + c0 + cl;
            tile[cl * 65 + pl] = yA[ix] + yB[ix] + yC[ix];
        }
    }
    __syncthreads();
    {
        int pl = threadIdx.x & 63;
        int cg = threadIdx.x >> 6;
        #pragma unroll
        for (int cc = 0; cc < 16; ++cc) {
            int cloc = cc * 4 + cg;
            int c = c0 + cloc;
            size_t o = ((size_t)b * CC + c) * LL + p0 + pl;
            out[o] = tile[cloc * 65 + pl] + feat[o] * D[c];
        }
    }
}

extern "C" void kernel_launch(void* const* d_in, const int* in_sizes, int n_in,
                              void* d_out, int out_size, void* d_ws, size_t ws_size,
                              hipStream_t stream)
{
    const float* feat  = (const float*)d_in[0];
    const float* A_log = (const float*)d_in[1];
    const float* D     = (const float*)d_in[2];
    const float* Wd    = (const float*)d_in[3];
    const float* bd    = (const float*)d_in[4];
    const float* WB    = (const float*)d_in[5];
    const float* WC    = (const float*)d_in[6];
    float* out = (float*)d_out;

    float* ws  = (float*)d_ws;
    float* du  = ws;                                      //  4,194,304 (float2 pairs)
    float* Bm  = du  + (size_t)4194304;                   //    131,072
    float* Cm  = Bm  + (size_t)131072;                    //    131,072
    float* P   = Cm  + (size_t)131072;                    //  3,145,728 (3 cls)
    float* S   = P   + (size_t)3145728;                   //  3,145,728
    float* Hin = S   + (size_t)3145728;                   //  4,194,304 (4 dirs)
    float* yA  = Hin + (size_t)4194304;                   //  2,097,152
    float* yB  = yA  + (size_t)2097152;                   //  2,097,152
    float* yC  = yB  + (size_t)2097152;                   //  2,097,152

    k1_delta_gemm<<<512, 256, 0, stream>>>(feat, Wd, bd, WB, WC, du, Bm, Cm);
    p1_aggr<<<768, 256, 0, stream>>>((const float2*)du, Bm, A_log, P, S);
    p2_scan<<<256, 128, 0, stream>>>(P, S, Hin);
    p3_replay<<<768, 256, 0, stream>>>((const float2*)du, Bm, Cm, A_log, Hin, yA, yB, yC);
    k6_reduce<<<512, 256, 0, stream>>>(feat, D, yA, yB, yC, out);
}